// Round 10
// baseline (712.500 us; speedup 1.0000x reference)
//
#include <hip/hip_runtime.h>
#include <cstdint>
#include <cstddef>

// LIF cell: new_v = DECAY*v0 + (1-DECAY)*([inputs|z0] @ [w_in; w_rec_nd]) - z0
// B=4096, K=8192, N=4096. Outputs f32 (v, z, r).
// Precision: 2-way f16 split, UNSCALED residuals -> single accumulator:
//   acc = aH.wH (K 8192) + aH.wL' (8192) + aL'.wH (4096) = 256*S
// GEMM core: 256x256 tile, BK=64, 8 waves (2Mx4N), 16x16x32 MFMA,
// double-buffered 128KiB LDS, pre-swizzled-source XOR staging (0 conflicts),
// 2 sync points/K-tile, setprio around MFMA clusters.
// ROUND 10 change: ALL four next-tile stages issue at P0 (the nxt buffer is
// provably free after sync2(prev): barrier implies all prev-tile LDS reads
// retired). Every global_load_lds now gets >=3 phases (~1000 cyc) of flight
// >= HBM latency (~900 cyc) -> sync1 stall eliminated. Ledger (issue order
// A0,B0,A1,B1): sync1 WAITV(8) drains exactly B1(cur); sync2 WAITV(2) drains
// A0/B0/A1(next), leaves B1(next) flying. NT tail reverted (r9: +26MB writes,
// -4.5% MfmaUtil). Merged single prep dispatch kept.

typedef __attribute__((ext_vector_type(8))) _Float16 f16x8;
typedef __attribute__((ext_vector_type(4))) float f32x4;

#define DECAY_F 0.9512294245007140f
#define ONEMD_F 0.0487705754992860f

#define BAR() __builtin_amdgcn_s_barrier()
#define WAITV(n) asm volatile("s_waitcnt vmcnt(" #n ")" ::: "memory")

__device__ __forceinline__ void gl2lds16(const void* g, void* s) {
  __builtin_amdgcn_global_load_lds(
      (const __attribute__((address_space(1))) uint32_t*)g,
      (__attribute__((address_space(3))) uint32_t*)s, 16, 0, 0);
}

// ---------------------------------------------------------------------------
// prep_all: blocks [0,8192): weight transpose+split; [8192,16384): A split.
// wtH[n][k] = f16(256*w), wtL = 256*w - wtH;  w = w_in | w_rec (diag zeroed)
// aH[b][0:4096]=f16(inputs), aH[b][4096:8192]=f16(z0) (exact),
// aL[b][0:4096] = inputs - f16(inputs)
// ---------------------------------------------------------------------------
__global__ __launch_bounds__(256) void prep_all(const float* __restrict__ w_in,
                                                const float* __restrict__ w_rec,
                                                const float* __restrict__ inputs,
                                                const float* __restrict__ z0,
                                                _Float16* __restrict__ wtH,
                                                _Float16* __restrict__ wtL,
                                                _Float16* __restrict__ aH,
                                                _Float16* __restrict__ aL) {
  int bid = blockIdx.x;
  int t = threadIdx.x;
  if (bid < 8192) {
    __shared__ float s[64][65];
    int kt = bid >> 6, nt = bid & 63;
    int k0 = kt * 64, n0 = nt * 64;

    bool rec = (k0 >= 4096);
    const float* W = rec ? w_rec : w_in;
    int kb = rec ? (k0 - 4096) : k0;

    int cr = t >> 4;
    int cc = (t & 15) * 4;
#pragma unroll
    for (int j = 0; j < 4; ++j) {
      int r = cr + j * 16;
      float4 v = *reinterpret_cast<const float4*>(&W[(size_t)(kb + r) * 4096 + n0 + cc]);
      s[r][cc + 0] = v.x; s[r][cc + 1] = v.y; s[r][cc + 2] = v.z; s[r][cc + 3] = v.w;
    }
    __syncthreads();
#pragma unroll
    for (int j = 0; j < 2; ++j) {
      int g = t + 256 * j;
      int n = g >> 3;
      int k8 = (g & 7) * 8;
      f16x8 h, l;
#pragma unroll
      for (int i = 0; i < 8; ++i) {
        float w = s[k8 + i][n];
        int gk = k0 + k8 + i;
        if (rec && (gk - 4096) == (n0 + n)) w = 0.0f;
        w *= 256.0f;
        _Float16 hi = (_Float16)w;
        h[i] = hi;
        l[i] = (_Float16)(w - (float)hi);
      }
      size_t o = (size_t)(n0 + n) * 8192 + (size_t)(k0 + k8);
      *reinterpret_cast<f16x8*>(&wtH[o]) = h;
      *reinterpret_cast<f16x8*>(&wtL[o]) = l;
    }
  } else {
    int g = (bid - 8192) * 256 + t;  // 0 .. 2M-1
    int b = g >> 9;
    int k8 = (g & 511) * 8;

    const float4* pi = reinterpret_cast<const float4*>(&inputs[(size_t)b * 4096 + k8]);
    float4 x = pi[0], y = pi[1];
    float xs[8] = {x.x, x.y, x.z, x.w, y.x, y.y, y.z, y.w};
    f16x8 h, l;
#pragma unroll
    for (int i = 0; i < 8; ++i) {
      _Float16 hi = (_Float16)xs[i];
      h[i] = hi;
      l[i] = (_Float16)(xs[i] - (float)hi);
    }
    *reinterpret_cast<f16x8*>(&aH[(size_t)b * 8192 + k8]) = h;
    *reinterpret_cast<f16x8*>(&aL[(size_t)b * 4096 + k8]) = l;

    const float4* pz = reinterpret_cast<const float4*>(&z0[(size_t)b * 4096 + k8]);
    x = pz[0]; y = pz[1];
    float zs[8] = {x.x, x.y, x.z, x.w, y.x, y.y, y.z, y.w};
    f16x8 hz;
#pragma unroll
    for (int i = 0; i < 8; ++i) hz[i] = (_Float16)zs[i];
    *reinterpret_cast<f16x8*>(&aH[(size_t)b * 8192 + 4096 + k8]) = hz;
  }
}

// ---------------------------------------------------------------------------
// lif_gemm: 256x256 tile, 16x16x32 MFMA, 320 K-tiles, 2 sync points/tile.
// LDS (131072 B dynamic): buf b: A at b*65536 + half*16384,
//                         B at b*65536 + 32768 + half*16384.
// ---------------------------------------------------------------------------
#define DO_MFMA(AF, BF, MH, NH)                                              \
  __builtin_amdgcn_s_setprio(1);                                             \
  _Pragma("unroll")                                                          \
  for (int j_ = 0; j_ < 4; ++j_)                                             \
    _Pragma("unroll")                                                        \
    for (int i_ = 0; i_ < 2; ++i_)                                           \
      _Pragma("unroll")                                                      \
      for (int kh_ = 0; kh_ < 2; ++kh_)                                      \
        acc[MH][j_][NH][i_] = __builtin_amdgcn_mfma_f32_16x16x32_f16(        \
            AF[j_][kh_], BF[i_][kh_], acc[MH][j_][NH][i_], 0, 0, 0);         \
  __builtin_amdgcn_s_setprio(0);

template <int FUSED>
__global__ __launch_bounds__(512, 2) void lif_gemm(const _Float16* __restrict__ aH,
                                                   const _Float16* __restrict__ aL,
                                                   const _Float16* __restrict__ wtH,
                                                   const _Float16* __restrict__ wtL,
                                                   const float* __restrict__ v0,
                                                   const int* __restrict__ r0,
                                                   const float* __restrict__ z0,
                                                   float* __restrict__ o0,
                                                   float* __restrict__ o1,
                                                   float* __restrict__ o2) {
  extern __shared__ __align__(16) char lds[];

  int bid = blockIdx.x;
  int swz = (bid & 7) * 32 + (bid >> 3);  // XCD swizzle, bijective (256%8==0)
  int bm = swz >> 4, bn = swz & 15;
  int row0 = bm << 8, col0 = bn << 8;

  int t = threadIdx.x;
  int w = t >> 6, lane = t & 63;
  int wm = w >> 2, wn = w & 3;
  int wm16 = wm << 4, wn16 = wn << 4;
  int rl = lane & 15, klane = lane >> 4;
  int lr = lane >> 3;         // row within 8-row staging chunk
  int sg = (lane & 7) ^ lr;   // pre-swizzled source 16B group

  f32x4 acc[2][4][2][2];
#pragma unroll
  for (int a = 0; a < 2; ++a)
#pragma unroll
    for (int b = 0; b < 4; ++b)
#pragma unroll
      for (int c = 0; c < 2; ++c)
#pragma unroll
        for (int d = 0; d < 2; ++d) acc[a][b][c][d] = (f32x4){0.f, 0.f, 0.f, 0.f};

  auto stageA = [&](int buf, int half, const _Float16* A, int strA, int kb) {
#pragma unroll
    for (int c = 0; c < 2; ++c) {
      int gr = row0 + (half << 7) + (w << 4) + (c << 3) + lr;
      const char* src = (const char*)A + (((size_t)gr * strA + kb) << 1) + (sg << 4);
      char* dst = lds + (buf << 16) + (half << 14) + ((w * 2 + c) << 10);
      gl2lds16(src, dst);
    }
  };
  auto stageB = [&](int buf, int half, const _Float16* Bp, int kb) {
#pragma unroll
    for (int c = 0; c < 2; ++c) {
      int gc = col0 + (half << 7) + (w << 4) + (c << 3) + lr;
      const char* src = (const char*)Bp + (((size_t)gc * 8192 + kb) << 1) + (sg << 4);
      char* dst = lds + (buf << 16) + 32768 + (half << 14) + ((w * 2 + c) << 10);
      gl2lds16(src, dst);
    }
  };
  auto ldsFragA = [&](int buf, int half, int j, int kh) -> f16x8 {
    int r = (j << 5) + wm16 + rl;
    int kb = (kh << 6) + (klane << 4);
    int byte = (buf << 16) + (half << 14) + (r << 7) + (kb ^ ((r & 7) << 4));
    return *(const f16x8*)(lds + byte);
  };
  auto ldsFragB = [&](int buf, int half, int i, int kh) -> f16x8 {
    int r = (i << 6) + wn16 + rl;
    int kb = (kh << 6) + (klane << 4);
    int byte = (buf << 16) + 32768 + (half << 14) + (r << 7) + (kb ^ ((r & 7) << 4));
    return *(const f16x8*)(lds + byte);
  };
  auto segOf = [&](int tt, const _Float16*& A, const _Float16*& Bp, int& kb, int& strA) {
    if (tt < 128)      { A = aH; Bp = wtH; kb = tt << 6;         strA = 8192; }
    else if (tt < 256) { A = aH; Bp = wtL; kb = (tt - 128) << 6; strA = 8192; }
    else               { A = aL; Bp = wtH; kb = (tt - 256) << 6; strA = 4096; }
  };

  // prologue: stage tile 0 in ledger order A0,B0,A1,B1; leave B1 in flight
  {
    const _Float16 *A, *Bp; int kb, strA;
    segOf(0, A, Bp, kb, strA);
    stageA(0, 0, A, strA, kb);
    stageB(0, 0, Bp, kb);
    stageA(0, 1, A, strA, kb);
    stageB(0, 1, Bp, kb);
  }
  WAITV(2);
  BAR();

  f16x8 a0f[4][2], a1f[4][2], b0f[2][2], b1f[2][2];

  for (int tau = 0; tau < 320; ++tau) {
    int cur = tau & 1, nxt = cur ^ 1;
    int nt = tau + 1;
    bool hn = nt < 320;
    const _Float16 *An = aH, *Bn = wtH; int kbn = 0, strAn = 8192;
    if (hn) segOf(nt, An, Bn, kbn, strAn);

    // ---- P0: read a0f,b0f; issue ALL next-tile stages (nxt buffer provably
    // free: sync2(prev) barrier implies all prev-tile LDS reads retired).
#pragma unroll
    for (int j = 0; j < 4; ++j)
#pragma unroll
      for (int kh = 0; kh < 2; ++kh) a0f[j][kh] = ldsFragA(cur, 0, j, kh);
#pragma unroll
    for (int i = 0; i < 2; ++i)
#pragma unroll
      for (int kh = 0; kh < 2; ++kh) b0f[i][kh] = ldsFragB(cur, 0, i, kh);
    if (hn) {
      stageA(nxt, 0, An, strAn, kbn);
      stageB(nxt, 0, Bn, kbn);
      stageA(nxt, 1, An, strAn, kbn);
      stageB(nxt, 1, Bn, kbn);
    }
    DO_MFMA(a0f, b0f, 0, 0);

    // ---- P1: quadrant (1,0)
#pragma unroll
    for (int j = 0; j < 4; ++j)
#pragma unroll
      for (int kh = 0; kh < 2; ++kh) a1f[j][kh] = ldsFragA(cur, 1, j, kh);
    DO_MFMA(a1f, b0f, 1, 0);
    // SYNC 1: drain B1(cur) (staged at prev-P0, ~5 phases of flight).
    // outstanding: B1cur(2) + next8 = 10 -> WAITV(8) drains exactly B1cur.
    if (tau == 319) { WAITV(0); } else { WAITV(8); }
    BAR();

    // ---- P2: quadrant (0,1)
#pragma unroll
    for (int i = 0; i < 2; ++i)
#pragma unroll
      for (int kh = 0; kh < 2; ++kh) b1f[i][kh] = ldsFragB(cur, 1, i, kh);
    DO_MFMA(a0f, b1f, 0, 1);

    // ---- P3: quadrant (1,1)
    DO_MFMA(a1f, b1f, 1, 1);
    // SYNC 2: drain A0/B0/A1(next) (3 phases of flight); B1(next) stays
    // in flight. Also fences the cur-buffer overwrite.
    if (hn) { WAITV(2); }
    BAR();
  }

  // ---- fused tail (C/D 16x16: col = lane&15, row = (lane>>4)*4 + jj)
  const float invW = 1.0f / 256.0f;
#pragma unroll
  for (int mh = 0; mh < 2; ++mh)
#pragma unroll
    for (int j = 0; j < 4; ++j)
#pragma unroll
      for (int nh = 0; nh < 2; ++nh)
#pragma unroll
        for (int i = 0; i < 2; ++i) {
          int row = row0 + (mh << 7) + (j << 5) + wm16 + (klane << 2);
          int col = col0 + (nh << 7) + (i << 6) + wn16 + rl;
#pragma unroll
          for (int jj = 0; jj < 4; ++jj) {
            size_t idx = (size_t)(row + jj) * 4096 + col;
            float S = acc[mh][j][nh][i][jj] * invW;
            if (FUSED) {
              float nv = DECAY_F * v0[idx] + (ONEMD_F * S - z0[idx]);
              bool spike = (nv > 1.0f) && (r0[idx] <= 0);
              int nr = r0[idx] - 1 + (spike ? 5 : 0);
              nr = nr < 0 ? 0 : (nr > 5 ? 5 : nr);
              o0[idx] = nv;
              o1[idx] = spike ? 1.0f : 0.0f;
              o2[idx] = (float)nr;
            } else {
              o0[idx] = S;
            }
          }
        }
}

// ---------------------------------------------------------------------------
// fallback epilogue (non-fused path): elementwise LIF, S in place in outv.
// ---------------------------------------------------------------------------
__global__ __launch_bounds__(256) void lif_epilogue(const float* __restrict__ v0,
                                                    const int* __restrict__ r0,
                                                    const float* __restrict__ z0,
                                                    float* __restrict__ outv,
                                                    float* __restrict__ outz,
                                                    float* __restrict__ outr) {
  size_t i = ((size_t)blockIdx.x * 256 + threadIdx.x) * 4;
  float4 S = *reinterpret_cast<const float4*>(&outv[i]);
  float4 V = *reinterpret_cast<const float4*>(&v0[i]);
  float4 Z = *reinterpret_cast<const float4*>(&z0[i]);
  int4 R = *reinterpret_cast<const int4*>(&r0[i]);
  float s[4] = {S.x, S.y, S.z, S.w};
  float v[4] = {V.x, V.y, V.z, V.w};
  float z[4] = {Z.x, Z.y, Z.z, Z.w};
  int r[4] = {R.x, R.y, R.z, R.w};
  float4 ov, oz, orr;
  float* po[3] = {&ov.x, &oz.x, &orr.x};
#pragma unroll
  for (int j = 0; j < 4; ++j) {
    float nv = DECAY_F * v[j] + (ONEMD_F * s[j] - z[j]);
    bool spike = (nv > 1.0f) && (r[j] <= 0);
    int nr = r[j] - 1 + (spike ? 5 : 0);
    nr = nr < 0 ? 0 : (nr > 5 ? 5 : nr);
    po[0][j] = nv;
    po[1][j] = spike ? 1.0f : 0.0f;
    po[2][j] = (float)nr;
  }
  *reinterpret_cast<float4*>(&outv[i]) = ov;
  *reinterpret_cast<float4*>(&outz[i]) = oz;
  *reinterpret_cast<float4*>(&outr[i]) = orr;
}

// ---------------------------------------------------------------------------
extern "C" void kernel_launch(void* const* d_in, const int* in_sizes, int n_in,
                              void* d_out, int out_size, void* d_ws, size_t ws_size,
                              hipStream_t stream) {
  const float* inputs = (const float*)d_in[0];
  const float* v0     = (const float*)d_in[1];
  const int*   r0     = (const int*)d_in[2];
  const float* z0     = (const float*)d_in[3];
  const float* w_in   = (const float*)d_in[4];
  const float* w_rec  = (const float*)d_in[5];

  const size_t MB = (size_t)1 << 20;
  if (ws_size < 128 * MB) return;  // need at least the weight planes
  bool fused = (ws_size >= 224 * MB);

  _Float16* wtH = (_Float16*)d_ws;
  _Float16* wtL = (_Float16*)((char*)d_ws + 64 * MB);

  float* out  = (float*)d_out;
  float* outv = out;
  float* outz = out + (size_t)4096 * 4096;
  float* outr = out + (size_t)2 * 4096 * 4096;

  _Float16* aH;
  _Float16* aL;
  if (fused) {
    aH = (_Float16*)((char*)d_ws + 128 * MB);  // 64 MB
    aL = (_Float16*)((char*)d_ws + 192 * MB);  // 32 MB
  } else {
    aH = (_Float16*)outz;  // scratch until epilogue overwrites
    aL = (_Float16*)outr;
  }

  (void)hipFuncSetAttribute((const void*)lif_gemm<1>,
                            hipFuncAttributeMaxDynamicSharedMemorySize, 131072);
  (void)hipFuncSetAttribute((const void*)lif_gemm<0>,
                            hipFuncAttributeMaxDynamicSharedMemorySize, 131072);

  prep_all<<<dim3(16384), dim3(256), 0, stream>>>(w_in, w_rec, inputs, z0,
                                                  wtH, wtL, aH, aL);
  if (fused) {
    lif_gemm<1><<<dim3(256), dim3(512), 131072, stream>>>(
        aH, aL, wtH, wtL, v0, r0, z0, outv, outz, outr);
  } else {
    lif_gemm<0><<<dim3(256), dim3(512), 131072, stream>>>(
        aH, aL, wtH, wtL, v0, r0, z0, outv, outz, outr);
    lif_epilogue<<<dim3(16384), dim3(256), 0, stream>>>(v0, r0, z0, outv, outz, outr);
  }
}

// Round 11
// 661.839 us; speedup vs baseline: 1.0765x; 1.0765x over previous
//
#include <hip/hip_runtime.h>
#include <cstdint>
#include <cstddef>

// LIF cell: new_v = DECAY*v0 + (1-DECAY)*([inputs|z0] @ [w_in; w_rec_nd]) - z0
// B=4096, K=8192, N=4096. Outputs f32 (v, z, r).
// Precision: 2-way f16 split, UNSCALED residuals -> single accumulator:
//   acc = aH.wH (K 8192) + aH.wL' (8192) + aL'.wH (4096) = 256*S
// GEMM core: ROUND-7 EXACT (best measured: 664.6us total, 54.7% MfmaUtil,
// 0 bank conflicts): 256x256 tile, BK=64, 8 waves (2Mx4N), 16x16x32 MFMA,
// double-buffered 128KiB LDS, pre-swizzled-source XOR staging, 2 sync
// points/K-tile (counted vmcnt, never 0 mid-loop), setprio around MFMA,
// stages spread ONE per phase (bunching proven harmful in r8/r10).
// + merged single prep dispatch (r9, neutral-positive). NT tail reverted
// (r9: -4.5% MfmaUtil). Fused LIF tail (ws>=224MB proven available).

typedef __attribute__((ext_vector_type(8))) _Float16 f16x8;
typedef __attribute__((ext_vector_type(4))) float f32x4;

#define DECAY_F 0.9512294245007140f
#define ONEMD_F 0.0487705754992860f

#define BAR() __builtin_amdgcn_s_barrier()
#define WAITV(n) asm volatile("s_waitcnt vmcnt(" #n ")" ::: "memory")

__device__ __forceinline__ void gl2lds16(const void* g, void* s) {
  __builtin_amdgcn_global_load_lds(
      (const __attribute__((address_space(1))) uint32_t*)g,
      (__attribute__((address_space(3))) uint32_t*)s, 16, 0, 0);
}

// ---------------------------------------------------------------------------
// prep_all: blocks [0,8192): weight transpose+split; [8192,16384): A split.
// wtH[n][k] = f16(256*w), wtL = 256*w - wtH;  w = w_in | w_rec (diag zeroed)
// aH[b][0:4096]=f16(inputs), aH[b][4096:8192]=f16(z0) (exact),
// aL[b][0:4096] = inputs - f16(inputs)
// ---------------------------------------------------------------------------
__global__ __launch_bounds__(256) void prep_all(const float* __restrict__ w_in,
                                                const float* __restrict__ w_rec,
                                                const float* __restrict__ inputs,
                                                const float* __restrict__ z0,
                                                _Float16* __restrict__ wtH,
                                                _Float16* __restrict__ wtL,
                                                _Float16* __restrict__ aH,
                                                _Float16* __restrict__ aL) {
  int bid = blockIdx.x;
  int t = threadIdx.x;
  if (bid < 8192) {
    __shared__ float s[64][65];
    int kt = bid >> 6, nt = bid & 63;
    int k0 = kt * 64, n0 = nt * 64;

    bool rec = (k0 >= 4096);
    const float* W = rec ? w_rec : w_in;
    int kb = rec ? (k0 - 4096) : k0;

    int cr = t >> 4;
    int cc = (t & 15) * 4;
#pragma unroll
    for (int j = 0; j < 4; ++j) {
      int r = cr + j * 16;
      float4 v = *reinterpret_cast<const float4*>(&W[(size_t)(kb + r) * 4096 + n0 + cc]);
      s[r][cc + 0] = v.x; s[r][cc + 1] = v.y; s[r][cc + 2] = v.z; s[r][cc + 3] = v.w;
    }
    __syncthreads();
#pragma unroll
    for (int j = 0; j < 2; ++j) {
      int g = t + 256 * j;
      int n = g >> 3;
      int k8 = (g & 7) * 8;
      f16x8 h, l;
#pragma unroll
      for (int i = 0; i < 8; ++i) {
        float w = s[k8 + i][n];
        int gk = k0 + k8 + i;
        if (rec && (gk - 4096) == (n0 + n)) w = 0.0f;
        w *= 256.0f;
        _Float16 hi = (_Float16)w;
        h[i] = hi;
        l[i] = (_Float16)(w - (float)hi);
      }
      size_t o = (size_t)(n0 + n) * 8192 + (size_t)(k0 + k8);
      *reinterpret_cast<f16x8*>(&wtH[o]) = h;
      *reinterpret_cast<f16x8*>(&wtL[o]) = l;
    }
  } else {
    int g = (bid - 8192) * 256 + t;  // 0 .. 2M-1
    int b = g >> 9;
    int k8 = (g & 511) * 8;

    const float4* pi = reinterpret_cast<const float4*>(&inputs[(size_t)b * 4096 + k8]);
    float4 x = pi[0], y = pi[1];
    float xs[8] = {x.x, x.y, x.z, x.w, y.x, y.y, y.z, y.w};
    f16x8 h, l;
#pragma unroll
    for (int i = 0; i < 8; ++i) {
      _Float16 hi = (_Float16)xs[i];
      h[i] = hi;
      l[i] = (_Float16)(xs[i] - (float)hi);
    }
    *reinterpret_cast<f16x8*>(&aH[(size_t)b * 8192 + k8]) = h;
    *reinterpret_cast<f16x8*>(&aL[(size_t)b * 4096 + k8]) = l;

    const float4* pz = reinterpret_cast<const float4*>(&z0[(size_t)b * 4096 + k8]);
    x = pz[0]; y = pz[1];
    float zs[8] = {x.x, x.y, x.z, x.w, y.x, y.y, y.z, y.w};
    f16x8 hz;
#pragma unroll
    for (int i = 0; i < 8; ++i) hz[i] = (_Float16)zs[i];
    *reinterpret_cast<f16x8*>(&aH[(size_t)b * 8192 + 4096 + k8]) = hz;
  }
}

// ---------------------------------------------------------------------------
// lif_gemm: 256x256 tile, 16x16x32 MFMA, 320 K-tiles, 2 sync points/tile.
// LDS (131072 B dynamic): buf b: A at b*65536 + half*16384,
//                         B at b*65536 + 32768 + half*16384.
// Phases: P0=(0,0) stage A0n; P1=(1,0) stage A1n, sync1; P2=(0,1) stage B0n;
// P3=(1,1) stage B1n, sync2. One stage per phase (spread, not bunched).
// ---------------------------------------------------------------------------
#define DO_MFMA(AF, BF, MH, NH)                                              \
  __builtin_amdgcn_s_setprio(1);                                             \
  _Pragma("unroll")                                                          \
  for (int j_ = 0; j_ < 4; ++j_)                                             \
    _Pragma("unroll")                                                        \
    for (int i_ = 0; i_ < 2; ++i_)                                           \
      _Pragma("unroll")                                                      \
      for (int kh_ = 0; kh_ < 2; ++kh_)                                      \
        acc[MH][j_][NH][i_] = __builtin_amdgcn_mfma_f32_16x16x32_f16(        \
            AF[j_][kh_], BF[i_][kh_], acc[MH][j_][NH][i_], 0, 0, 0);         \
  __builtin_amdgcn_s_setprio(0);

template <int FUSED>
__global__ __launch_bounds__(512, 2) void lif_gemm(const _Float16* __restrict__ aH,
                                                   const _Float16* __restrict__ aL,
                                                   const _Float16* __restrict__ wtH,
                                                   const _Float16* __restrict__ wtL,
                                                   const float* __restrict__ v0,
                                                   const int* __restrict__ r0,
                                                   const float* __restrict__ z0,
                                                   float* __restrict__ o0,
                                                   float* __restrict__ o1,
                                                   float* __restrict__ o2) {
  extern __shared__ __align__(16) char lds[];

  int bid = blockIdx.x;
  int swz = (bid & 7) * 32 + (bid >> 3);  // XCD swizzle, bijective (256%8==0)
  int bm = swz >> 4, bn = swz & 15;
  int row0 = bm << 8, col0 = bn << 8;

  int t = threadIdx.x;
  int w = t >> 6, lane = t & 63;
  int wm = w >> 2, wn = w & 3;
  int wm16 = wm << 4, wn16 = wn << 4;
  int rl = lane & 15, klane = lane >> 4;
  int lr = lane >> 3;         // row within 8-row staging chunk
  int sg = (lane & 7) ^ lr;   // pre-swizzled source 16B group

  f32x4 acc[2][4][2][2];
#pragma unroll
  for (int a = 0; a < 2; ++a)
#pragma unroll
    for (int b = 0; b < 4; ++b)
#pragma unroll
      for (int c = 0; c < 2; ++c)
#pragma unroll
        for (int d = 0; d < 2; ++d) acc[a][b][c][d] = (f32x4){0.f, 0.f, 0.f, 0.f};

  auto stageA = [&](int buf, int half, const _Float16* A, int strA, int kb) {
#pragma unroll
    for (int c = 0; c < 2; ++c) {
      int gr = row0 + (half << 7) + (w << 4) + (c << 3) + lr;
      const char* src = (const char*)A + (((size_t)gr * strA + kb) << 1) + (sg << 4);
      char* dst = lds + (buf << 16) + (half << 14) + ((w * 2 + c) << 10);
      gl2lds16(src, dst);
    }
  };
  auto stageB = [&](int buf, int half, const _Float16* Bp, int kb) {
#pragma unroll
    for (int c = 0; c < 2; ++c) {
      int gc = col0 + (half << 7) + (w << 4) + (c << 3) + lr;
      const char* src = (const char*)Bp + (((size_t)gc * 8192 + kb) << 1) + (sg << 4);
      char* dst = lds + (buf << 16) + 32768 + (half << 14) + ((w * 2 + c) << 10);
      gl2lds16(src, dst);
    }
  };
  auto ldsFragA = [&](int buf, int half, int j, int kh) -> f16x8 {
    int r = (j << 5) + wm16 + rl;
    int kb = (kh << 6) + (klane << 4);
    int byte = (buf << 16) + (half << 14) + (r << 7) + (kb ^ ((r & 7) << 4));
    return *(const f16x8*)(lds + byte);
  };
  auto ldsFragB = [&](int buf, int half, int i, int kh) -> f16x8 {
    int r = (i << 6) + wn16 + rl;
    int kb = (kh << 6) + (klane << 4);
    int byte = (buf << 16) + 32768 + (half << 14) + (r << 7) + (kb ^ ((r & 7) << 4));
    return *(const f16x8*)(lds + byte);
  };
  auto segOf = [&](int tt, const _Float16*& A, const _Float16*& Bp, int& kb, int& strA) {
    if (tt < 128)      { A = aH; Bp = wtH; kb = tt << 6;         strA = 8192; }
    else if (tt < 256) { A = aH; Bp = wtL; kb = (tt - 128) << 6; strA = 8192; }
    else               { A = aL; Bp = wtH; kb = (tt - 256) << 6; strA = 4096; }
  };

  // prologue: stage tile 0 (A0,A1,B0,B1); B1 may stay in flight
  {
    const _Float16 *A, *Bp; int kb, strA;
    segOf(0, A, Bp, kb, strA);
    stageA(0, 0, A, strA, kb);
    stageA(0, 1, A, strA, kb);
    stageB(0, 0, Bp, kb);
    stageB(0, 1, Bp, kb);
  }
  WAITV(2);
  BAR();

  f16x8 a0f[4][2], a1f[4][2], b0f[2][2], b1f[2][2];

  for (int tau = 0; tau < 320; ++tau) {
    int cur = tau & 1, nxt = cur ^ 1;
    int nt = tau + 1;
    bool hn = nt < 320;
    const _Float16 *An = aH, *Bn = wtH; int kbn = 0, strAn = 8192;
    if (hn) segOf(nt, An, Bn, kbn, strAn);

    // ---- P0: quadrant (0,0); stage next A0   (no barrier)
#pragma unroll
    for (int j = 0; j < 4; ++j)
#pragma unroll
      for (int kh = 0; kh < 2; ++kh) a0f[j][kh] = ldsFragA(cur, 0, j, kh);
#pragma unroll
    for (int i = 0; i < 2; ++i)
#pragma unroll
      for (int kh = 0; kh < 2; ++kh) b0f[i][kh] = ldsFragB(cur, 0, i, kh);
    if (hn) stageA(nxt, 0, An, strAn, kbn);
    DO_MFMA(a0f, b0f, 0, 0);

    // ---- P1: quadrant (1,0); stage next A1
#pragma unroll
    for (int j = 0; j < 4; ++j)
#pragma unroll
      for (int kh = 0; kh < 2; ++kh) a1f[j][kh] = ldsFragA(cur, 1, j, kh);
    if (hn) stageA(nxt, 1, An, strAn, kbn);
    DO_MFMA(a1f, b0f, 1, 0);
    // SYNC 1: drain cur-B1 staging (issued prev-P3) before anyone reads it.
    // outstanding: prevB1(2) + A0n(2) + A1n(2) = 6 -> WAITV(4) drains prevB1.
    if (tau == 319) { WAITV(0); } else { WAITV(4); }
    BAR();

    // ---- P2: quadrant (0,1); stage next B0
#pragma unroll
    for (int i = 0; i < 2; ++i)
#pragma unroll
      for (int kh = 0; kh < 2; ++kh) b1f[i][kh] = ldsFragB(cur, 1, i, kh);
    if (hn) stageB(nxt, 0, Bn, kbn);
    DO_MFMA(a0f, b1f, 0, 1);

    // ---- P3: quadrant (1,1); stage next B1
    if (hn) stageB(nxt, 1, Bn, kbn);
    DO_MFMA(a1f, b1f, 1, 1);
    // SYNC 2: next A0/A1/B0 landed (B1 stays in flight); also fences the
    // cur-buffer overwrite (all cur reads retired via per-wave lgkm waits).
    if (hn) { WAITV(2); }
    BAR();
  }

  // ---- fused tail (C/D 16x16: col = lane&15, row = (lane>>4)*4 + jj)
  const float invW = 1.0f / 256.0f;
#pragma unroll
  for (int mh = 0; mh < 2; ++mh)
#pragma unroll
    for (int j = 0; j < 4; ++j)
#pragma unroll
      for (int nh = 0; nh < 2; ++nh)
#pragma unroll
        for (int i = 0; i < 2; ++i) {
          int row = row0 + (mh << 7) + (j << 5) + wm16 + (klane << 2);
          int col = col0 + (nh << 7) + (i << 6) + wn16 + rl;
#pragma unroll
          for (int jj = 0; jj < 4; ++jj) {
            size_t idx = (size_t)(row + jj) * 4096 + col;
            float S = acc[mh][j][nh][i][jj] * invW;
            if (FUSED) {
              float nv = DECAY_F * v0[idx] + (ONEMD_F * S - z0[idx]);
              bool spike = (nv > 1.0f) && (r0[idx] <= 0);
              int nr = r0[idx] - 1 + (spike ? 5 : 0);
              nr = nr < 0 ? 0 : (nr > 5 ? 5 : nr);
              o0[idx] = nv;
              o1[idx] = spike ? 1.0f : 0.0f;
              o2[idx] = (float)nr;
            } else {
              o0[idx] = S;
            }
          }
        }
}

// ---------------------------------------------------------------------------
// fallback epilogue (non-fused path): elementwise LIF, S in place in outv.
// ---------------------------------------------------------------------------
__global__ __launch_bounds__(256) void lif_epilogue(const float* __restrict__ v0,
                                                    const int* __restrict__ r0,
                                                    const float* __restrict__ z0,
                                                    float* __restrict__ outv,
                                                    float* __restrict__ outz,
                                                    float* __restrict__ outr) {
  size_t i = ((size_t)blockIdx.x * 256 + threadIdx.x) * 4;
  float4 S = *reinterpret_cast<const float4*>(&outv[i]);
  float4 V = *reinterpret_cast<const float4*>(&v0[i]);
  float4 Z = *reinterpret_cast<const float4*>(&z0[i]);
  int4 R = *reinterpret_cast<const int4*>(&r0[i]);
  float s[4] = {S.x, S.y, S.z, S.w};
  float v[4] = {V.x, V.y, V.z, V.w};
  float z[4] = {Z.x, Z.y, Z.z, Z.w};
  int r[4] = {R.x, R.y, R.z, R.w};
  float4 ov, oz, orr;
  float* po[3] = {&ov.x, &oz.x, &orr.x};
#pragma unroll
  for (int j = 0; j < 4; ++j) {
    float nv = DECAY_F * v[j] + (ONEMD_F * s[j] - z[j]);
    bool spike = (nv > 1.0f) && (r[j] <= 0);
    int nr = r[j] - 1 + (spike ? 5 : 0);
    nr = nr < 0 ? 0 : (nr > 5 ? 5 : nr);
    po[0][j] = nv;
    po[1][j] = spike ? 1.0f : 0.0f;
    po[2][j] = (float)nr;
  }
  *reinterpret_cast<float4*>(&outv[i]) = ov;
  *reinterpret_cast<float4*>(&outz[i]) = oz;
  *reinterpret_cast<float4*>(&outr[i]) = orr;
}

// ---------------------------------------------------------------------------
extern "C" void kernel_launch(void* const* d_in, const int* in_sizes, int n_in,
                              void* d_out, int out_size, void* d_ws, size_t ws_size,
                              hipStream_t stream) {
  const float* inputs = (const float*)d_in[0];
  const float* v0     = (const float*)d_in[1];
  const int*   r0     = (const int*)d_in[2];
  const float* z0     = (const float*)d_in[3];
  const float* w_in   = (const float*)d_in[4];
  const float* w_rec  = (const float*)d_in[5];

  const size_t MB = (size_t)1 << 20;
  if (ws_size < 128 * MB) return;  // need at least the weight planes
  bool fused = (ws_size >= 224 * MB);

  _Float16* wtH = (_Float16*)d_ws;
  _Float16* wtL = (_Float16*)((char*)d_ws + 64 * MB);

  float* out  = (float*)d_out;
  float* outv = out;
  float* outz = out + (size_t)4096 * 4096;
  float* outr = out + (size_t)2 * 4096 * 4096;

  _Float16* aH;
  _Float16* aL;
  if (fused) {
    aH = (_Float16*)((char*)d_ws + 128 * MB);  // 64 MB
    aL = (_Float16*)((char*)d_ws + 192 * MB);  // 32 MB
  } else {
    aH = (_Float16*)outz;  // scratch until epilogue overwrites
    aL = (_Float16*)outr;
  }

  (void)hipFuncSetAttribute((const void*)lif_gemm<1>,
                            hipFuncAttributeMaxDynamicSharedMemorySize, 131072);
  (void)hipFuncSetAttribute((const void*)lif_gemm<0>,
                            hipFuncAttributeMaxDynamicSharedMemorySize, 131072);

  prep_all<<<dim3(16384), dim3(256), 0, stream>>>(w_in, w_rec, inputs, z0,
                                                  wtH, wtL, aH, aL);
  if (fused) {
    lif_gemm<1><<<dim3(256), dim3(512), 131072, stream>>>(
        aH, aL, wtH, wtL, v0, r0, z0, outv, outz, outr);
  } else {
    lif_gemm<0><<<dim3(256), dim3(512), 131072, stream>>>(
        aH, aL, wtH, wtL, v0, r0, z0, outv, outz, outr);
    lif_epilogue<<<dim3(16384), dim3(256), 0, stream>>>(v0, r0, z0, outv, outz, outr);
  }
}